// Round 2
// baseline (278.830 us; speedup 1.0000x reference)
//
#include <hip/hip_runtime.h>

#define TPB 128

// ---- bucketed-permutation parameters ----
#define NPART 128          // partitions of the element range (K1/K3 grid)
#define NBIN  1024         // user-index buckets: users[i]>>10, table window = 128 KB
#define TPB1  1024

typedef float f2 __attribute__((ext_vector_type(2)));

// K1: per-partition histogram of user buckets (LDS atomics only, no pre-zeroing).
__global__ __launch_bounds__(TPB1) void hist_kernel(
    const int* __restrict__ users, int n, int chunk, int* __restrict__ ghist) {
    __shared__ int lh[NBIN];
    int bk = blockIdx.x, t = threadIdx.x;
    lh[t] = 0;
    __syncthreads();
    int lo = bk * chunk, hi = min(n, lo + chunk);
    for (int i = lo + t; i < hi; i += TPB1)
        atomicAdd(&lh[users[i] >> 10], 1);
    __syncthreads();
    ghist[bk * NBIN + t] = lh[t];
}

// K2: single block. Column-scan over partitions (per-bin running base) +
// block-wide exclusive scan of bin totals (Hillis-Steele).
__global__ __launch_bounds__(TPB1) void scan_kernel(
    const int* __restrict__ ghist, int* __restrict__ gbase,
    int* __restrict__ binstart) {
    __shared__ int tot[NBIN];
    int t = threadIdx.x;
    int run = 0;
#pragma unroll 8
    for (int bk = 0; bk < NPART; ++bk) {
        int v = ghist[bk * NBIN + t];
        gbase[bk * NBIN + t] = run;
        run += v;
    }
    tot[t] = run;
    __syncthreads();
    for (int off = 1; off < NBIN; off <<= 1) {
        int y = (t >= off) ? tot[t - off] : 0;
        __syncthreads();
        tot[t] += y;
        __syncthreads();
    }
    binstart[t] = tot[t] - run;   // exclusive of own column total
}

// K3: scatter element ids into bucket-ordered perm via LDS cursors.
// Rank order within (partition,bin) is arbitrary -> results still bit-exact
// per element (each i computed independently).
__global__ __launch_bounds__(TPB1) void scatter_kernel(
    const int* __restrict__ users, int n, int chunk,
    const int* __restrict__ gbase, const int* __restrict__ binstart,
    int* __restrict__ perm) {
    __shared__ int cur[NBIN];
    int bk = blockIdx.x, t = threadIdx.x;
    cur[t] = gbase[bk * NBIN + t] + binstart[t];
    __syncthreads();
    int lo = bk * chunk, hi = min(n, lo + chunk);
    for (int i = lo + t; i < hi; i += TPB1) {
        int b = users[i] >> 10;
        int pos = atomicAdd(&cur[b], 1);
        perm[pos] = i;
    }
}

// u-table gather regions (per block): 2 waves x 8 regions.
// Region (w,s) = 8 rows x 128 B, lane-linear (global_load_lds constraint),
// stride 1040 B (16 B pad) so read-phase b128 bank-group = (s+q)&7 -> floor.
// Elements are processed in bucket order (via perm): a wave's 64 u-rows fall
// in a ~128 KB table window -> DRAM page locality; duplicate rows adjacent.
#define RSTRIDE 1040
#define NREG    16            // (TPB/64) * 8

__global__ __launch_bounds__(TPB, 4) void mf_kernel(
    const int* __restrict__ perm,
    const int* __restrict__ users, const int* __restrict__ movies,
    const char* __restrict__ uemb,   // fp32 [1e6][32] = 128 B rows
    const char* __restrict__ memb,   // fp32 [1e5][32]
    const float* __restrict__ w1,    // fp32 [8][96] = [8][grp0|grp1|grp2]
    const float* __restrict__ b1,
    const float* __restrict__ w2,
    const float* __restrict__ b2,
    float* __restrict__ out, int n) {
    __shared__ char lds[NREG * RSTRIDE];   // 16640 B

    int t = threadIdx.x;
    int gid = blockIdx.x * TPB + t;
    int gc = (gid < n) ? gid : (n - 1);
    int j = perm[gc];                // bucket-ordered element id
    int uidx = users[j];             // random 4B in 4MB buffer (L2/L3-resident)
    int midx = movies[j];

    int l    = t & 63;
    int w    = t >> 6;
    int slot = l >> 3;               // row-slot this lane serves in each gather
    int c    = l & 7;                // 16 B chunk this lane fetches

    // 8 coalesced row-gathers (u table) per wave, all in flight at once.
#pragma unroll
    for (int s = 0; s < 8; ++s) {
        int ru = __shfl(uidx, s * 8 + slot, 64);
        __builtin_amdgcn_global_load_lds(
            (const __attribute__((address_space(1))) void*)(uemb + (size_t)ru * 128 + c * 16),
            (__attribute__((address_space(3))) void*)&lds[(w * 8 + s) * RSTRIDE],
            16, 0, 0);
    }

    // Movie row: per-lane scattered dwordx4 from the cache-resident table.
    const char* mrow_g = memb + (size_t)midx * 128;
    float4 m4[8];
#pragma unroll
    for (int q = 0; q < 8; ++q)
        m4[q] = *(const float4*)(mrow_g + q * 16);

    // Wait for this wave's global_load_lds writes (vmcnt is per-wave; regions
    // are wave-local so no cross-wave barrier is required).
    asm volatile("s_waitcnt vmcnt(0)" ::: "memory");
    __builtin_amdgcn_sched_barrier(0);

    // My element's u-row: region (w, l>>3), row-slot l&7.
    const char* urow = &lds[(w * 8 + ((t >> 3) & 7)) * RSTRIDE + (t & 7) * 128];

    // Weights read directly from w1 (uniform indices -> scalar loads, K$-cached).
    // f2 pair index into w1: j*48 + grp*16 + d   (grp: 0 = u*m, 1 = u, 2 = m)
    const f2* w1p = (const f2*)w1;
    f2 h2[8];
#pragma unroll
    for (int jj = 0; jj < 8; ++jj) { h2[jj].x = b1[jj]; h2[jj].y = 0.0f; }

#pragma unroll
    for (int q = 0; q < 8; ++q) {
        float4 u4 = *(const float4*)(urow + q * 16);
        f2 u0; u0.x = u4.x;    u0.y = u4.y;
        f2 u1; u1.x = u4.z;    u1.y = u4.w;
        f2 m0; m0.x = m4[q].x; m0.y = m4[q].y;
        f2 m1; m1.x = m4[q].z; m1.y = m4[q].w;
        f2 p0 = u0 * m0;             // v_pk_mul_f32
        f2 p1 = u1 * m1;
        int d0 = 2 * q, d1 = 2 * q + 1;
#pragma unroll
        for (int jj = 0; jj < 8; ++jj) {
            h2[jj] = __builtin_elementwise_fma(p0, w1p[jj * 48 +      d0], h2[jj]);
            h2[jj] = __builtin_elementwise_fma(u0, w1p[jj * 48 + 16 + d0], h2[jj]);
            h2[jj] = __builtin_elementwise_fma(m0, w1p[jj * 48 + 32 + d0], h2[jj]);
            h2[jj] = __builtin_elementwise_fma(p1, w1p[jj * 48 +      d1], h2[jj]);
            h2[jj] = __builtin_elementwise_fma(u1, w1p[jj * 48 + 16 + d1], h2[jj]);
            h2[jj] = __builtin_elementwise_fma(m1, w1p[jj * 48 + 32 + d1], h2[jj]);
        }
    }

    float z = b2[0];
#pragma unroll
    for (int jj = 0; jj < 8; ++jj) {
        float hj = h2[jj].x + h2[jj].y;
        z = fmaf(fmaxf(hj, 0.0f), w2[jj], z);
    }

    if (gid < n) out[j] = 1.0f / (1.0f + __expf(-z));
}

extern "C" void kernel_launch(void* const* d_in, const int* in_sizes, int n_in,
                              void* d_out, int out_size, void* d_ws, size_t ws_size,
                              hipStream_t stream) {
    const int* users  = (const int*)d_in[0];
    const int* movies = (const int*)d_in[1];
    const char* uemb  = (const char*)d_in[2];    // fp32 [1e6, 32]
    const char* memb  = (const char*)d_in[3];    // fp32 [1e5, 32]
    const float* w1   = (const float*)d_in[4];   // fp32 [8, 96]
    const float* b1   = (const float*)d_in[5];   // fp32 [8]
    const float* w2   = (const float*)d_in[6];   // fp32 [1, 8]
    const float* b2   = (const float*)d_in[7];   // fp32 [1]
    float* out = (float*)d_out;

    int n = in_sizes[0];
    int chunk = (n + NPART - 1) / NPART;

    // workspace layout (ints): ghist[NPART*NBIN] | gbase[NPART*NBIN] |
    //                          binstart[NBIN]    | perm[n]
    int* ghist    = (int*)d_ws;
    int* gbase    = ghist + NPART * NBIN;
    int* binstart = gbase + NPART * NBIN;
    int* perm     = binstart + NBIN;

    hist_kernel   <<<NPART, TPB1, 0, stream>>>(users, n, chunk, ghist);
    scan_kernel   <<<1,     TPB1, 0, stream>>>(ghist, gbase, binstart);
    scatter_kernel<<<NPART, TPB1, 0, stream>>>(users, n, chunk, gbase, binstart, perm);
    mf_kernel<<<(n + TPB - 1) / TPB, TPB, 0, stream>>>(
        perm, users, movies, uemb, memb, w1, b1, w2, b2, out, n);
}

// Round 3
// 221.867 us; speedup vs baseline: 1.2567x; 1.2567x over previous
//
#include <hip/hip_runtime.h>

#define TPB 128

typedef float f2 __attribute__((ext_vector_type(2)));

// u-table gather regions (per block): 2 waves x 8 regions.
// Region (w,s) = 8 rows x 128 B, lane-linear (global_load_lds constraint),
// stride 1040 B (16 B pad) so read-phase b128 bank-group = (s+q)&7 -> floor.
// Movie table (12.8 MB) is L2/L3-resident: gathered per-lane direct to VGPRs,
// no LDS staging. LDS 16.6 KB/block -> LDS-capped at 9 blocks/CU = 18 waves.
// launch_bounds(128,8) lifts the occupancy target so LDS is the only cap
// (VGPR=60 fits the 64-reg budget for 8 waves/EU).
// LDS regions are wave-local (both write and read index by w), so no
// __syncthreads needed: per-wave s_waitcnt vmcnt(0) suffices.
#define RSTRIDE 1040
#define NREG    16            // (TPB/64) * 8

__global__ __launch_bounds__(TPB, 8) void mf_kernel(
    const int* __restrict__ users, const int* __restrict__ movies,
    const char* __restrict__ uemb,   // fp32 [1e6][32] = 128 B rows
    const char* __restrict__ memb,   // fp32 [1e5][32]
    const float* __restrict__ w1,    // fp32 [8][96] = [8][grp0|grp1|grp2]
    const float* __restrict__ b1,
    const float* __restrict__ w2,
    const float* __restrict__ b2,
    float* __restrict__ out, int n) {
    __shared__ char lds[NREG * RSTRIDE];   // 16640 B

    int t = threadIdx.x;
    int i = blockIdx.x * TPB + t;
    int ic = (i < n) ? i : (n - 1);
    int uidx = users[ic];            // coalesced; element t's index lives in lane t&63 of wave t>>6
    int midx = movies[ic];

    int l    = t & 63;
    int w    = t >> 6;
    int slot = l >> 3;               // row-slot this lane serves in each gather
    int c    = l & 7;                // 16 B chunk this lane fetches

    // 8 coalesced row-gathers (u table) per wave, all in flight at once.
#pragma unroll
    for (int s = 0; s < 8; ++s) {
        int ru = __shfl(uidx, s * 8 + slot, 64);
        __builtin_amdgcn_global_load_lds(
            (const __attribute__((address_space(1))) void*)(uemb + (size_t)ru * 128 + c * 16),
            (__attribute__((address_space(3))) void*)&lds[(w * 8 + s) * RSTRIDE],
            16, 0, 0);
    }

    // Movie row: per-lane scattered dwordx4 from the cache-resident table.
    const char* mrow_g = memb + (size_t)midx * 128;
    float4 m4[8];
#pragma unroll
    for (int q = 0; q < 8; ++q)
        m4[q] = *(const float4*)(mrow_g + q * 16);

    // Wait for this wave's global_load_lds writes (vmcnt is per-wave; regions
    // are wave-local so no cross-wave barrier is required).
    asm volatile("s_waitcnt vmcnt(0)" ::: "memory");
    __builtin_amdgcn_sched_barrier(0);

    // My element's u-row: region (w, l>>3), row-slot l&7.
    const char* urow = &lds[(w * 8 + ((t >> 3) & 7)) * RSTRIDE + (t & 7) * 128];

    // Weights read directly from w1 (uniform indices -> scalar loads, K$-cached).
    // f2 pair index into w1: j*48 + grp*16 + d   (grp: 0 = u*m, 1 = u, 2 = m)
    const f2* w1p = (const f2*)w1;
    f2 h2[8];
#pragma unroll
    for (int j = 0; j < 8; ++j) { h2[j].x = b1[j]; h2[j].y = 0.0f; }

#pragma unroll
    for (int q = 0; q < 8; ++q) {
        float4 u4 = *(const float4*)(urow + q * 16);
        f2 u0; u0.x = u4.x;    u0.y = u4.y;
        f2 u1; u1.x = u4.z;    u1.y = u4.w;
        f2 m0; m0.x = m4[q].x; m0.y = m4[q].y;
        f2 m1; m1.x = m4[q].z; m1.y = m4[q].w;
        f2 p0 = u0 * m0;             // v_pk_mul_f32
        f2 p1 = u1 * m1;
        int d0 = 2 * q, d1 = 2 * q + 1;
#pragma unroll
        for (int j = 0; j < 8; ++j) {
            h2[j] = __builtin_elementwise_fma(p0, w1p[j * 48 +      d0], h2[j]);
            h2[j] = __builtin_elementwise_fma(u0, w1p[j * 48 + 16 + d0], h2[j]);
            h2[j] = __builtin_elementwise_fma(m0, w1p[j * 48 + 32 + d0], h2[j]);
            h2[j] = __builtin_elementwise_fma(p1, w1p[j * 48 +      d1], h2[j]);
            h2[j] = __builtin_elementwise_fma(u1, w1p[j * 48 + 16 + d1], h2[j]);
            h2[j] = __builtin_elementwise_fma(m1, w1p[j * 48 + 32 + d1], h2[j]);
        }
    }

    float z = b2[0];
#pragma unroll
    for (int j = 0; j < 8; ++j) {
        float hj = h2[j].x + h2[j].y;
        z = fmaf(fmaxf(hj, 0.0f), w2[j], z);
    }

    if (i < n) out[i] = 1.0f / (1.0f + __expf(-z));
}

extern "C" void kernel_launch(void* const* d_in, const int* in_sizes, int n_in,
                              void* d_out, int out_size, void* d_ws, size_t ws_size,
                              hipStream_t stream) {
    const int* users  = (const int*)d_in[0];
    const int* movies = (const int*)d_in[1];
    const char* uemb  = (const char*)d_in[2];    // fp32 [1e6, 32]
    const char* memb  = (const char*)d_in[3];    // fp32 [1e5, 32]
    const float* w1   = (const float*)d_in[4];   // fp32 [8, 96]
    const float* b1   = (const float*)d_in[5];   // fp32 [8]
    const float* w2   = (const float*)d_in[6];   // fp32 [1, 8]
    const float* b2   = (const float*)d_in[7];   // fp32 [1]
    float* out = (float*)d_out;

    int n = in_sizes[0];

    mf_kernel<<<(n + TPB - 1) / TPB, TPB, 0, stream>>>(
        users, movies, uemb, memb, w1, b1, w2, b2, out, n);
}